// Round 1
// baseline (993.758 us; speedup 1.0000x reference)
//
#include <hip/hip_runtime.h>
#include <math.h>

#define B_ 16
#define S_ 512
#define D_ 768
#define H_ 12
#define DH_ 64
#define BH_ (B_*H_)     // 192
#define MTOT (B_*S_)    // 8192
#define QPW 4           // query rows per wave in attention

// ---------------------------------------------------------------------------
// Fused QKV projection: C[m,n] = sum_k X[m,k]*W[n,k] + bias[n]
// blockIdx.z: 0=Q -> [BH,S,DH], 1=K -> [BH,DH,S] (transposed!), 2=V -> [BH,S,DH]
// ---------------------------------------------------------------------------
__global__ __launch_bounds__(256)
void proj_kernel(const float* __restrict__ X,
                 const float* __restrict__ Wq, const float* __restrict__ bq,
                 const float* __restrict__ Wk, const float* __restrict__ bk,
                 const float* __restrict__ Wv, const float* __restrict__ bv,
                 float* __restrict__ outq, float* __restrict__ outkT,
                 float* __restrict__ outv)
{
    const int z = blockIdx.z;
    const float* W    = (z==0) ? Wq : (z==1) ? Wk : Wv;
    const float* bias = (z==0) ? bq : (z==1) ? bk : bv;
    float* out        = (z==0) ? outq : (z==1) ? outkT : outv;

    __shared__ float As[64][17];  // [m][k], +1 pad
    __shared__ float Bs[64][17];  // [n][k]

    const int tid  = threadIdx.x;
    const int row0 = blockIdx.y * 64;
    const int col0 = blockIdx.x * 64;
    const int tx = tid & 15, ty = tid >> 4;

    float acc[4][4];
    #pragma unroll
    for (int i=0;i<4;i++)
        #pragma unroll
        for (int j=0;j<4;j++) acc[i][j]=0.f;

    for (int k0 = 0; k0 < D_; k0 += 16) {
        #pragma unroll
        for (int l=0;l<4;l++){
            int e = tid + l*256;
            int r = e >> 4, c = e & 15;
            As[r][c] = X[(size_t)(row0 + r)*D_ + k0 + c];
            Bs[r][c] = W[(size_t)(col0 + r)*D_ + k0 + c];
        }
        __syncthreads();
        #pragma unroll
        for (int kk=0; kk<16; kk++){
            float a[4], b[4];
            #pragma unroll
            for (int i=0;i<4;i++) a[i] = As[ty*4+i][kk];
            #pragma unroll
            for (int j=0;j<4;j++) b[j] = Bs[tx*4+j][kk];
            #pragma unroll
            for (int i=0;i<4;i++)
                #pragma unroll
                for (int j=0;j<4;j++)
                    acc[i][j] += a[i]*b[j];
        }
        __syncthreads();
    }

    #pragma unroll
    for (int i=0;i<4;i++){
        int m  = row0 + ty*4 + i;
        int bb = m / S_, s = m % S_;
        #pragma unroll
        for (int j=0;j<4;j++){
            int n = col0 + tx*4 + j;
            int h = n / DH_, d = n & (DH_-1);
            float val = acc[i][j] + bias[n];
            if (z == 1) out[(((size_t)bb*H_ + h)*DH_ + d)*S_ + s] = val;  // K^T
            else        out[(((size_t)bb*H_ + h)*S_ + s)*DH_ + d] = val;  // Q,V
        }
    }
}

// ---------------------------------------------------------------------------
// Sparsemax attention. One wave = QPW query rows; lane holds 8 keys (lane+64i).
// tau via binary search on f(tau)=sum(max(z-tau,0)) then exact refinement.
// PV uses ballot over nonzero probs (sparsemax support is tiny).
// ---------------------------------------------------------------------------
__global__ __launch_bounds__(256)
void attn_kernel(const float* __restrict__ q,    // [BH, S, DH]
                 const float* __restrict__ kT,   // [BH, DH, S]
                 const float* __restrict__ v,    // [BH, S, DH]
                 const float* __restrict__ mask, // [B, S]
                 float* __restrict__ out)        // [B, S, D]
{
    const int lane = threadIdx.x & 63;
    const int wave = threadIdx.x >> 6;
    const int rowsPerBlock = 4 * QPW;            // 16
    const int blocksPerBH  = S_ / rowsPerBlock;  // 32
    const int bh    = blockIdx.x / blocksPerBH;
    const int qbase = (blockIdx.x % blocksPerBH) * rowsPerBlock + wave * QPW;
    const int b = bh / H_;
    const int h = bh % H_;

    const float* kbase = kT + (size_t)bh * DH_ * S_;
    const float* vbase = v  + (size_t)bh * S_ * DH_;

    // lane holds element [lane] of each of its QPW query rows
    float qreg[QPW];
    #pragma unroll
    for (int r=0;r<QPW;r++)
        qreg[r] = q[((size_t)bh * S_ + qbase + r)*DH_ + lane];

    float mv[8];
    #pragma unroll
    for (int i=0;i<8;i++) mv[i] = mask[b*S_ + lane + 64*i];

    float zs[QPW][8];
    #pragma unroll
    for (int r=0;r<QPW;r++)
        #pragma unroll
        for (int i=0;i<8;i++) zs[r][i]=0.f;

    // scores: z[r][t] = sum_d q[r][d] * kT[d][t]
    for (int d=0; d<DH_; d++){
        float qv[QPW];
        #pragma unroll
        for (int r=0;r<QPW;r++) qv[r] = __shfl(qreg[r], d, 64);
        const float* kd = kbase + (size_t)d*S_;
        #pragma unroll
        for (int i=0;i<8;i++){
            float kvv = kd[lane + 64*i];
            #pragma unroll
            for (int r=0;r<QPW;r++) zs[r][i] += qv[r]*kvv;
        }
    }
    const float scale = 0.125f;  // 1/sqrt(64)
    #pragma unroll
    for (int r=0;r<QPW;r++)
        #pragma unroll
        for (int i=0;i<8;i++)
            zs[r][i] = zs[r][i]*scale + mv[i];

    #pragma unroll
    for (int r=0;r<QPW;r++){
        // wave-wide max
        float m = zs[r][0];
        #pragma unroll
        for (int i=1;i<8;i++) m = fmaxf(m, zs[r][i]);
        #pragma unroll
        for (int off=32; off; off>>=1) m = fmaxf(m, __shfl_xor(m, off, 64));

        // binary search tau in [m-1, m]
        float lo = m - 1.f, hi = m;
        for (int it=0; it<26; it++){
            float mid  = 0.5f*(lo+hi);
            float fsum = 0.f;
            #pragma unroll
            for (int i=0;i<8;i++) fsum += fmaxf(zs[r][i]-mid, 0.f);
            #pragma unroll
            for (int off=32; off; off>>=1) fsum += __shfl_xor(fsum, off, 64);
            if (fsum >= 1.f) lo = mid; else hi = mid;
        }
        // exact refinement on the resolved support set
        float theta = 0.5f*(lo+hi);
        float cnt = 0.f, ssum = 0.f;
        #pragma unroll
        for (int i=0;i<8;i++){
            if (zs[r][i] > theta){ cnt += 1.f; ssum += zs[r][i]; }
        }
        #pragma unroll
        for (int off=32; off; off>>=1){
            cnt  += __shfl_xor(cnt,  off, 64);
            ssum += __shfl_xor(ssum, off, 64);
        }
        float tau = (ssum - 1.f) / cnt;

        // ctx[d=lane] = sum_t p_t * V[t][d]; iterate only nonzero-prob keys
        float ctx = 0.f;
        #pragma unroll
        for (int i=0;i<8;i++){
            float p = fmaxf(zs[r][i]-tau, 0.f);
            unsigned long long mk = __ballot(p > 0.f);
            while (mk){
                int src = __ffsll((long long)mk) - 1;
                mk &= mk - 1;
                float pv = __shfl(p, src, 64);
                ctx += pv * vbase[(size_t)(src + 64*i)*DH_ + lane];
            }
        }
        out[((size_t)(b*S_ + qbase + r))*D_ + h*DH_ + lane] = ctx;
    }
}

// ---------------------------------------------------------------------------
extern "C" void kernel_launch(void* const* d_in, const int* in_sizes, int n_in,
                              void* d_out, int out_size, void* d_ws, size_t ws_size,
                              hipStream_t stream) {
    const float* hs   = (const float*)d_in[0];
    const float* mask = (const float*)d_in[1];
    const float* Wq   = (const float*)d_in[2];
    const float* bq   = (const float*)d_in[3];
    const float* Wk   = (const float*)d_in[4];
    const float* bk   = (const float*)d_in[5];
    const float* Wv   = (const float*)d_in[6];
    const float* bv   = (const float*)d_in[7];
    float* out = (float*)d_out;

    const size_t per = (size_t)BH_ * S_ * DH_;   // 6291456 floats
    float* ws  = (float*)d_ws;
    float* qb  = ws;
    float* kTb = ws + per;
    float* vb  = ws + 2*per;

    dim3 pgrid(D_/64, MTOT/64, 3);
    proj_kernel<<<pgrid, 256, 0, stream>>>(hs, Wq, bq, Wk, bk, Wv, bv, qb, kTb, vb);

    dim3 agrid(BH_ * (S_/16));
    attn_kernel<<<agrid, 256, 0, stream>>>(qb, kTb, vb, mask, out);
}

// Round 2
// 421.575 us; speedup vs baseline: 2.3573x; 2.3573x over previous
//
#include <hip/hip_runtime.h>
#include <math.h>

#define B_ 16
#define S_ 512
#define D_ 768
#define H_ 12
#define DH_ 64
#define BH_ (B_*H_)     // 192
#define MTOT (B_*S_)    // 8192
#define NTOT (3*D_)     // 2304
#define QPW 4

typedef unsigned short ushort_t;
typedef __attribute__((ext_vector_type(8))) short bf16x8;
typedef __attribute__((ext_vector_type(4))) float f32x4;

__device__ __forceinline__ unsigned short f2bf(float x){
    unsigned u = __float_as_uint(x);
    unsigned r = (u + 0x7FFFu + ((u >> 16) & 1u)) >> 16;
    return (unsigned short)r;
}
__device__ __forceinline__ float bf2f(unsigned short b){
    return __uint_as_float(((unsigned)b) << 16);
}

__device__ __forceinline__ void cp16(const void* g, void* l){
    __builtin_amdgcn_global_load_lds(
        (const __attribute__((address_space(1))) unsigned int*)g,
        (__attribute__((address_space(3))) unsigned int*)l, 16, 0, 0);
}

// ---------------------------------------------------------------------------
// f32 -> (hi, lo) bf16 split conversion, 4 elems/thread
// ---------------------------------------------------------------------------
__global__ __launch_bounds__(256)
void convert_hl(const float* __restrict__ src, ushort_t* __restrict__ hi,
                ushort_t* __restrict__ lo, int n4)
{
    int i = blockIdx.x * 256 + threadIdx.x;
    if (i >= n4) return;
    float4 x = ((const float4*)src)[i];
    union { ushort_t u[4]; uint2 v; } ph, pl;
    float xs[4] = {x.x, x.y, x.z, x.w};
    #pragma unroll
    for (int c = 0; c < 4; c++){
        unsigned short h = f2bf(xs[c]);
        ph.u[c] = h;
        pl.u[c] = f2bf(xs[c] - bf2f(h));
    }
    ((uint2*)hi)[i] = ph.v;
    ((uint2*)lo)[i] = pl.v;
}

// ---------------------------------------------------------------------------
// Split-bf16 MFMA GEMM: C[m,n] = sum_k X[m,k] * W[n,k] + bias, m<8192, n<2304
// n-tile selects matrix (Q/K/V); outputs in natural [BH,S,DH] layout.
// ---------------------------------------------------------------------------
#define BM 128
#define BN 128
#define BK 32

__global__ __launch_bounds__(256)
void gemm_split(const ushort_t* __restrict__ Ahi, const ushort_t* __restrict__ Alo,
                const ushort_t* __restrict__ Bhi, const ushort_t* __restrict__ Blo,
                const float* __restrict__ bq, const float* __restrict__ bk,
                const float* __restrict__ bv,
                float* __restrict__ outq, float* __restrict__ outk,
                float* __restrict__ outv)
{
    __shared__ ushort_t Ah[BM*BK], Al[BM*BK], Bh[BN*BK], Bl[BN*BK]; // 8 KB each

    const int tid  = threadIdx.x;
    const int lane = tid & 63, wave = tid >> 6;
    const int m0 = blockIdx.y * BM, n0 = blockIdx.x * BN;
    const int wm = (wave >> 1) * 64, wn = (wave & 1) * 64;

    f32x4 acc[4][4];
    #pragma unroll
    for (int i=0;i<4;i++)
        #pragma unroll
        for (int j=0;j<4;j++) acc[i][j] = (f32x4){0.f,0.f,0.f,0.f};

    // staging: thread covers elems [tid*8, tid*8+8) of each 128x32 tile (call 0)
    // and [2048 + tid*8, ...) (call 1). row = e/32, col = e%32.
    const int r0 = tid >> 2, c0 = (tid & 3) * 8;
    const size_t ga0 = (size_t)(m0 + r0)      * D_ + c0;
    const size_t ga1 = (size_t)(m0 + 64 + r0) * D_ + c0;
    const size_t gb0 = (size_t)(n0 + r0)      * D_ + c0;
    const size_t gb1 = (size_t)(n0 + 64 + r0) * D_ + c0;
    const int l0 = wave * 512;          // lds elem base, call 0
    const int l1 = 2048 + wave * 512;   // call 1

    const int fr = lane & 15, kc = (lane >> 4) * 8;

    for (int k0 = 0; k0 < D_; k0 += BK) {
        cp16(Ahi + ga0 + k0, Ah + l0);
        cp16(Ahi + ga1 + k0, Ah + l1);
        cp16(Alo + ga0 + k0, Al + l0);
        cp16(Alo + ga1 + k0, Al + l1);
        cp16(Bhi + gb0 + k0, Bh + l0);
        cp16(Bhi + gb1 + k0, Bh + l1);
        cp16(Blo + gb0 + k0, Bl + l0);
        cp16(Blo + gb1 + k0, Bl + l1);
        __syncthreads();

        bf16x8 fah[4], fal[4], fbh[4], fbl[4];
        #pragma unroll
        for (int i = 0; i < 4; i++){
            fah[i] = *(const bf16x8*)&Ah[(wm + i*16 + fr)*BK + kc];
            fal[i] = *(const bf16x8*)&Al[(wm + i*16 + fr)*BK + kc];
            fbh[i] = *(const bf16x8*)&Bh[(wn + i*16 + fr)*BK + kc];
            fbl[i] = *(const bf16x8*)&Bl[(wn + i*16 + fr)*BK + kc];
        }
        #pragma unroll
        for (int i = 0; i < 4; i++)
            #pragma unroll
            for (int j = 0; j < 4; j++){
                acc[i][j] = __builtin_amdgcn_mfma_f32_16x16x32_bf16(fah[i], fbh[j], acc[i][j], 0,0,0);
                acc[i][j] = __builtin_amdgcn_mfma_f32_16x16x32_bf16(fah[i], fbl[j], acc[i][j], 0,0,0);
                acc[i][j] = __builtin_amdgcn_mfma_f32_16x16x32_bf16(fal[i], fbh[j], acc[i][j], 0,0,0);
            }
        __syncthreads();
    }

    // epilogue: C/D layout col=lane&15, row=(lane>>4)*4+reg
    const int mat = n0 / D_;   // uniform per block (128 | 768)
    const float* bias = (mat==0) ? bq : (mat==1) ? bk : bv;
    float* outp       = (mat==0) ? outq : (mat==1) ? outk : outv;
    const int col = lane & 15, rbase = (lane >> 4) * 4;
    #pragma unroll
    for (int j = 0; j < 4; j++){
        int nn = n0 + wn + j*16 + col - mat*D_;
        int h = nn >> 6, d = nn & 63;
        float bsv = bias[nn];
        #pragma unroll
        for (int i = 0; i < 4; i++){
            #pragma unroll
            for (int r = 0; r < 4; r++){
                int m = m0 + wm + i*16 + rbase + r;
                int bb = m >> 9, s = m & 511;
                outp[(((size_t)bb*H_ + h)*S_ + s)*DH_ + d] = acc[i][j][r] + bsv;
            }
        }
    }
}

// ---------------------------------------------------------------------------
// k [BH,S,DH] -> kT [BH,DH,S] via LDS tiles
// ---------------------------------------------------------------------------
__global__ __launch_bounds__(256)
void transpose_k(const float* __restrict__ k, float* __restrict__ kT)
{
    __shared__ float Ts[64][65];
    const int bh = blockIdx.y, s0 = blockIdx.x * 64;
    const float* kb = k + ((size_t)bh * S_ + s0) * DH_;
    float* ko = kT + (size_t)bh * DH_ * S_;
    const int t = threadIdx.x;
    const int sr = t >> 4, c4 = (t & 15) * 4;
    #pragma unroll
    for (int p = 0; p < 4; p++){
        float4 v = *(const float4*)&kb[(p*16 + sr)*DH_ + c4];
        Ts[p*16 + sr][c4+0] = v.x;
        Ts[p*16 + sr][c4+1] = v.y;
        Ts[p*16 + sr][c4+2] = v.z;
        Ts[p*16 + sr][c4+3] = v.w;
    }
    __syncthreads();
    #pragma unroll
    for (int p = 0; p < 4; p++){
        int dr = p*16 + sr;
        float4 w;
        w.x = Ts[c4+0][dr]; w.y = Ts[c4+1][dr];
        w.z = Ts[c4+2][dr]; w.w = Ts[c4+3][dr];
        *(float4*)&ko[(size_t)dr * S_ + s0 + c4] = w;
    }
}

// ---------------------------------------------------------------------------
// Sparsemax attention (unchanged structure; search 16 iters + exact refine)
// ---------------------------------------------------------------------------
__global__ __launch_bounds__(256)
void attn_kernel(const float* __restrict__ q,    // [BH, S, DH]
                 const float* __restrict__ kT,   // [BH, DH, S]
                 const float* __restrict__ v,    // [BH, S, DH]
                 const float* __restrict__ mask, // [B, S]
                 float* __restrict__ out)        // [B, S, D]
{
    const int lane = threadIdx.x & 63;
    const int wave = threadIdx.x >> 6;
    const int rowsPerBlock = 4 * QPW;
    const int blocksPerBH  = S_ / rowsPerBlock;
    const int bh    = blockIdx.x / blocksPerBH;
    const int qbase = (blockIdx.x % blocksPerBH) * rowsPerBlock + wave * QPW;
    const int b = bh / H_;
    const int h = bh % H_;

    const float* kbase = kT + (size_t)bh * DH_ * S_;
    const float* vbase = v  + (size_t)bh * S_ * DH_;

    float qreg[QPW];
    #pragma unroll
    for (int r=0;r<QPW;r++)
        qreg[r] = q[((size_t)bh * S_ + qbase + r)*DH_ + lane];

    float mv[8];
    #pragma unroll
    for (int i=0;i<8;i++) mv[i] = mask[b*S_ + lane + 64*i];

    float zs[QPW][8];
    #pragma unroll
    for (int r=0;r<QPW;r++)
        #pragma unroll
        for (int i=0;i<8;i++) zs[r][i]=0.f;

    for (int d=0; d<DH_; d++){
        float qv[QPW];
        #pragma unroll
        for (int r=0;r<QPW;r++) qv[r] = __shfl(qreg[r], d, 64);
        const float* kd = kbase + (size_t)d*S_;
        #pragma unroll
        for (int i=0;i<8;i++){
            float kvv = kd[lane + 64*i];
            #pragma unroll
            for (int r=0;r<QPW;r++) zs[r][i] += qv[r]*kvv;
        }
    }
    const float scale = 0.125f;
    #pragma unroll
    for (int r=0;r<QPW;r++)
        #pragma unroll
        for (int i=0;i<8;i++)
            zs[r][i] = zs[r][i]*scale + mv[i];

    #pragma unroll
    for (int r=0;r<QPW;r++){
        float m = zs[r][0];
        #pragma unroll
        for (int i=1;i<8;i++) m = fmaxf(m, zs[r][i]);
        #pragma unroll
        for (int off=32; off; off>>=1) m = fmaxf(m, __shfl_xor(m, off, 64));

        float lo = m - 1.f, hi = m;
        for (int it=0; it<16; it++){
            float mid  = 0.5f*(lo+hi);
            float fsum = 0.f;
            #pragma unroll
            for (int i=0;i<8;i++) fsum += fmaxf(zs[r][i]-mid, 0.f);
            #pragma unroll
            for (int off=32; off; off>>=1) fsum += __shfl_xor(fsum, off, 64);
            if (fsum >= 1.f) lo = mid; else hi = mid;
        }
        float theta = 0.5f*(lo+hi);
        float cnt = 0.f, ssum = 0.f;
        #pragma unroll
        for (int i=0;i<8;i++){
            if (zs[r][i] > theta){ cnt += 1.f; ssum += zs[r][i]; }
        }
        #pragma unroll
        for (int off=32; off; off>>=1){
            cnt  += __shfl_xor(cnt,  off, 64);
            ssum += __shfl_xor(ssum, off, 64);
        }
        float tau = (ssum - 1.f) / cnt;

        float ctx = 0.f;
        #pragma unroll
        for (int i=0;i<8;i++){
            float p = fmaxf(zs[r][i]-tau, 0.f);
            unsigned long long mk = __ballot(p > 0.f);
            while (mk){
                int src = __ffsll((long long)mk) - 1;
                mk &= mk - 1;
                float pv = __shfl(p, src, 64);
                ctx += pv * vbase[(size_t)(src + 64*i)*DH_ + lane];
            }
        }
        out[((size_t)(b*S_ + qbase + r))*D_ + h*DH_ + lane] = ctx;
    }
}

// ---------------------------------------------------------------------------
extern "C" void kernel_launch(void* const* d_in, const int* in_sizes, int n_in,
                              void* d_out, int out_size, void* d_ws, size_t ws_size,
                              hipStream_t stream) {
    const float* hs   = (const float*)d_in[0];
    const float* mask = (const float*)d_in[1];
    const float* Wq   = (const float*)d_in[2];
    const float* bq   = (const float*)d_in[3];
    const float* Wk   = (const float*)d_in[4];
    const float* bk   = (const float*)d_in[5];
    const float* Wv   = (const float*)d_in[6];
    const float* bv   = (const float*)d_in[7];
    float* out = (float*)d_out;

    const size_t per = (size_t)BH_ * S_ * DH_;   // 6291456 floats
    float* ws  = (float*)d_ws;
    float* qb  = ws;
    float* vb  = qb + per;
    float* kb  = vb + per;
    float* region = kb + per;                    // shared: Xhi/Xlo then kT
    float* kTb = region;
    ushort_t* Xhi = (ushort_t*)region;           // per ushorts
    ushort_t* Xlo = Xhi + per;
    ushort_t* Whi = (ushort_t*)(region + per);   // 3*768*768 ushorts
    ushort_t* Wlo = Whi + (size_t)3*D_*D_;

    // 1) convert to split bf16
    convert_hl<<<(int)((per/4 + 255)/256), 256, 0, stream>>>(hs, Xhi, Xlo, (int)(per/4));
    const int wn4 = D_*D_/4;  // 147456
    convert_hl<<<(wn4+255)/256, 256, 0, stream>>>(Wq, Whi,           Wlo,           wn4);
    convert_hl<<<(wn4+255)/256, 256, 0, stream>>>(Wk, Whi +   D_*D_, Wlo +   D_*D_, wn4);
    convert_hl<<<(wn4+255)/256, 256, 0, stream>>>(Wv, Whi + 2*D_*D_, Wlo + 2*D_*D_, wn4);

    // 2) fused QKV projection via split-bf16 MFMA
    dim3 ggrid(NTOT/BN, MTOT/BM);   // (18, 64)
    gemm_split<<<ggrid, 256, 0, stream>>>(Xhi, Xlo, Whi, Wlo, bq, bk, bv, qb, kb, vb);

    // 3) K -> K^T (overwrites dead Xhi/Xlo region)
    dim3 tgrid(S_/64, BH_);
    transpose_k<<<tgrid, 256, 0, stream>>>(kb, kTb);

    // 4) sparsemax attention
    dim3 agrid(BH_ * (S_/16));
    attn_kernel<<<agrid, 256, 0, stream>>>(qb, kTb, vb, mask, out);
}

// Round 3
// 403.612 us; speedup vs baseline: 2.4622x; 1.0445x over previous
//
#include <hip/hip_runtime.h>
#include <math.h>

#define B_ 16
#define S_ 512
#define D_ 768
#define H_ 12
#define DH_ 64
#define BH_ (B_*H_)     // 192
#define MTOT (B_*S_)    // 8192
#define NTOT (3*D_)     // 2304

typedef unsigned short ushort_t;
typedef __attribute__((ext_vector_type(8))) short bf16x8;
typedef __attribute__((ext_vector_type(4))) float f32x4;

__device__ __forceinline__ unsigned short f2bf(float x){
    unsigned u = __float_as_uint(x);
    unsigned r = (u + 0x7FFFu + ((u >> 16) & 1u)) >> 16;
    return (unsigned short)r;
}
__device__ __forceinline__ float bf2f(unsigned short b){
    return __uint_as_float(((unsigned)b) << 16);
}

__device__ __forceinline__ void cp16(const void* g, void* l){
    __builtin_amdgcn_global_load_lds(
        (const __attribute__((address_space(1))) unsigned int*)g,
        (__attribute__((address_space(3))) unsigned int*)l, 16, 0, 0);
}

// ---------------------------------------------------------------------------
// f32 -> (hi, lo) bf16 split conversion, 4 elems/thread
// ---------------------------------------------------------------------------
__global__ __launch_bounds__(256)
void convert_hl(const float* __restrict__ src, ushort_t* __restrict__ hi,
                ushort_t* __restrict__ lo, int n4)
{
    int i = blockIdx.x * 256 + threadIdx.x;
    if (i >= n4) return;
    float4 x = ((const float4*)src)[i];
    union { ushort_t u[4]; uint2 v; } ph, pl;
    float xs[4] = {x.x, x.y, x.z, x.w};
    #pragma unroll
    for (int c = 0; c < 4; c++){
        unsigned short h = f2bf(xs[c]);
        ph.u[c] = h;
        pl.u[c] = f2bf(xs[c] - bf2f(h));
    }
    ((uint2*)hi)[i] = ph.v;
    ((uint2*)lo)[i] = pl.v;
}

// all three weight matrices in one launch (grid.z selects)
__global__ __launch_bounds__(256)
void convert_w(const float* __restrict__ Wq, const float* __restrict__ Wk,
               const float* __restrict__ Wv, ushort_t* __restrict__ hi,
               ushort_t* __restrict__ lo)
{
    const float* src = (blockIdx.z==0) ? Wq : (blockIdx.z==1) ? Wk : Wv;
    const int n4 = D_*D_/4;
    int i = blockIdx.x * 256 + threadIdx.x;
    if (i >= n4) return;
    size_t off4 = (size_t)blockIdx.z * n4;
    float4 x = ((const float4*)src)[i];
    union { ushort_t u[4]; uint2 v; } ph, pl;
    float xs[4] = {x.x, x.y, x.z, x.w};
    #pragma unroll
    for (int c = 0; c < 4; c++){
        unsigned short h = f2bf(xs[c]);
        ph.u[c] = h;
        pl.u[c] = f2bf(xs[c] - bf2f(h));
    }
    ((uint2*)hi)[off4 + i] = ph.v;
    ((uint2*)lo)[off4 + i] = pl.v;
}

// ---------------------------------------------------------------------------
// Split-bf16 MFMA GEMM: C[m,n] = sum_k X[m,k] * W[n,k] + bias
// mat 0 -> Q hi/lo bf16, mat 1 -> K hi/lo bf16, mat 2 -> V f32; all [BH,S,DH]
// ---------------------------------------------------------------------------
#define BM 128
#define BN 128
#define BK 32

__global__ __launch_bounds__(256)
void gemm_split(const ushort_t* __restrict__ Ahi, const ushort_t* __restrict__ Alo,
                const ushort_t* __restrict__ Bhi, const ushort_t* __restrict__ Blo,
                const float* __restrict__ bq, const float* __restrict__ bk,
                const float* __restrict__ bv,
                ushort_t* __restrict__ qhi, ushort_t* __restrict__ qlo,
                ushort_t* __restrict__ khi, ushort_t* __restrict__ klo,
                float* __restrict__ outv)
{
    __shared__ ushort_t Ah[BM*BK], Al[BM*BK], Bh[BN*BK], Bl[BN*BK];

    const int tid  = threadIdx.x;
    const int lane = tid & 63, wave = tid >> 6;
    const int m0 = blockIdx.y * BM, n0 = blockIdx.x * BN;
    const int wm = (wave >> 1) * 64, wn = (wave & 1) * 64;

    f32x4 acc[4][4];
    #pragma unroll
    for (int i=0;i<4;i++)
        #pragma unroll
        for (int j=0;j<4;j++) acc[i][j] = (f32x4){0.f,0.f,0.f,0.f};

    const int r0 = tid >> 2, c0 = (tid & 3) * 8;
    const size_t ga0 = (size_t)(m0 + r0)      * D_ + c0;
    const size_t ga1 = (size_t)(m0 + 64 + r0) * D_ + c0;
    const size_t gb0 = (size_t)(n0 + r0)      * D_ + c0;
    const size_t gb1 = (size_t)(n0 + 64 + r0) * D_ + c0;
    const int l0 = wave * 512;
    const int l1 = 2048 + wave * 512;

    const int fr = lane & 15, kc = (lane >> 4) * 8;

    for (int k0 = 0; k0 < D_; k0 += BK) {
        cp16(Ahi + ga0 + k0, Ah + l0);
        cp16(Ahi + ga1 + k0, Ah + l1);
        cp16(Alo + ga0 + k0, Al + l0);
        cp16(Alo + ga1 + k0, Al + l1);
        cp16(Bhi + gb0 + k0, Bh + l0);
        cp16(Bhi + gb1 + k0, Bh + l1);
        cp16(Blo + gb0 + k0, Bl + l0);
        cp16(Blo + gb1 + k0, Bl + l1);
        __syncthreads();

        bf16x8 fah[4], fal[4], fbh[4], fbl[4];
        #pragma unroll
        for (int i = 0; i < 4; i++){
            fah[i] = *(const bf16x8*)&Ah[(wm + i*16 + fr)*BK + kc];
            fal[i] = *(const bf16x8*)&Al[(wm + i*16 + fr)*BK + kc];
            fbh[i] = *(const bf16x8*)&Bh[(wn + i*16 + fr)*BK + kc];
            fbl[i] = *(const bf16x8*)&Bl[(wn + i*16 + fr)*BK + kc];
        }
        #pragma unroll
        for (int i = 0; i < 4; i++)
            #pragma unroll
            for (int j = 0; j < 4; j++){
                acc[i][j] = __builtin_amdgcn_mfma_f32_16x16x32_bf16(fah[i], fbh[j], acc[i][j], 0,0,0);
                acc[i][j] = __builtin_amdgcn_mfma_f32_16x16x32_bf16(fah[i], fbl[j], acc[i][j], 0,0,0);
                acc[i][j] = __builtin_amdgcn_mfma_f32_16x16x32_bf16(fal[i], fbh[j], acc[i][j], 0,0,0);
            }
        __syncthreads();
    }

    const int mat = n0 / D_;   // block-uniform
    const float* bias = (mat==0) ? bq : (mat==1) ? bk : bv;
    const int col = lane & 15, rbase = (lane >> 4) * 4;
    #pragma unroll
    for (int j = 0; j < 4; j++){
        int nn = n0 + wn + j*16 + col - mat*D_;
        int h = nn >> 6, d = nn & 63;
        float bsv = bias[nn];
        #pragma unroll
        for (int i = 0; i < 4; i++){
            #pragma unroll
            for (int r = 0; r < 4; r++){
                int m = m0 + wm + i*16 + rbase + r;
                int bb = m >> 9, s = m & 511;
                size_t idx = (((size_t)bb*H_ + h)*S_ + s)*DH_ + d;
                float val = acc[i][j][r] + bsv;
                if (mat == 2) outv[idx] = val;
                else {
                    ushort_t hv = f2bf(val);
                    ushort_t lv = f2bf(val - bf2f(hv));
                    if (mat == 0){ qhi[idx] = hv; qlo[idx] = lv; }
                    else         { khi[idx] = hv; klo[idx] = lv; }
                }
            }
        }
    }
}

// ---------------------------------------------------------------------------
// MFMA sparsemax attention. Block = (head, 64 q-rows), wave = 16 q-rows.
// Scores in 32 f32x4 accumulators (C layout: col=lane&15=key%16,
// row=quad*4+reg). Michelot fixed-point for tau; ballot-sparse PV.
// ---------------------------------------------------------------------------
__global__ __launch_bounds__(256)
void attn_mfma(const ushort_t* __restrict__ Qhi, const ushort_t* __restrict__ Qlo,
               const ushort_t* __restrict__ Khi, const ushort_t* __restrict__ Klo,
               const float* __restrict__ V, const float* __restrict__ mask,
               float* __restrict__ out)
{
    const int lane = threadIdx.x & 63;
    const int wave = threadIdx.x >> 6;
    const int fr = lane & 15, quad = lane >> 4;
    const int bh = blockIdx.x >> 3;
    const int q0 = (blockIdx.x & 7) * 64 + wave * 16;
    const int b = bh / H_, h = bh % H_;

    const size_t hb = (size_t)bh * S_ * DH_;

    // A frags: Q rows q0+fr, 8 contiguous d at s*32 + quad*8
    bf16x8 qh[2], ql[2];
    {
        const ushort_t* qp  = Qhi + hb + (size_t)(q0 + fr)*DH_ + quad*8;
        const ushort_t* qp2 = Qlo + hb + (size_t)(q0 + fr)*DH_ + quad*8;
        qh[0] = *(const bf16x8*)qp;   qh[1] = *(const bf16x8*)(qp + 32);
        ql[0] = *(const bf16x8*)qp2;  ql[1] = *(const bf16x8*)(qp2 + 32);
    }

    f32x4 acc[32];
    #pragma unroll
    for (int j=0;j<32;j++) acc[j] = (f32x4){0.f,0.f,0.f,0.f};

    #pragma unroll
    for (int j=0;j<32;j++){
        const ushort_t* kp  = Khi + hb + (size_t)(j*16 + fr)*DH_ + quad*8;
        const ushort_t* kp2 = Klo + hb + (size_t)(j*16 + fr)*DH_ + quad*8;
        bf16x8 kh0 = *(const bf16x8*)kp;
        bf16x8 kh1 = *(const bf16x8*)(kp + 32);
        bf16x8 kl0 = *(const bf16x8*)kp2;
        bf16x8 kl1 = *(const bf16x8*)(kp2 + 32);
        acc[j] = __builtin_amdgcn_mfma_f32_16x16x32_bf16(qh[0], kh0, acc[j], 0,0,0);
        acc[j] = __builtin_amdgcn_mfma_f32_16x16x32_bf16(qh[1], kh1, acc[j], 0,0,0);
        acc[j] = __builtin_amdgcn_mfma_f32_16x16x32_bf16(ql[0], kh0, acc[j], 0,0,0);
        acc[j] = __builtin_amdgcn_mfma_f32_16x16x32_bf16(ql[1], kh1, acc[j], 0,0,0);
        acc[j] = __builtin_amdgcn_mfma_f32_16x16x32_bf16(qh[0], kl0, acc[j], 0,0,0);
        acc[j] = __builtin_amdgcn_mfma_f32_16x16x32_bf16(qh[1], kl1, acc[j], 0,0,0);
    }

    // scale + additive mask (key index = j*16 + fr)
    const float* mrow = mask + b * S_;
    #pragma unroll
    for (int j=0;j<32;j++){
        float mv = mrow[j*16 + fr];
        #pragma unroll
        for (int r=0;r<4;r++) acc[j][r] = acc[j][r]*0.125f + mv;
    }

    // per-row max -> tau0 = max - 1. Rows live in 16-lane groups (same quad).
    float tau[4];
    #pragma unroll
    for (int r=0;r<4;r++){
        float m = acc[0][r];
        #pragma unroll
        for (int j=1;j<32;j++) m = fmaxf(m, acc[j][r]);
        #pragma unroll
        for (int off=1; off<16; off<<=1) m = fmaxf(m, __shfl_xor(m, off, 64));
        tau[r] = m - 1.0f;
    }

    // Michelot fixed-point: tau <- (sum_{z>tau} z - 1)/count; exact at fixpoint
    for (int it=0; it<16; it++){
        bool changed = false;
        #pragma unroll
        for (int r=0;r<4;r++){
            float s = 0.f, k = 0.f;
            #pragma unroll
            for (int j=0;j<32;j++){
                float z = acc[j][r];
                if (z > tau[r]){ s += z; k += 1.f; }
            }
            #pragma unroll
            for (int off=1; off<16; off<<=1){
                s += __shfl_xor(s, off, 64);
                k += __shfl_xor(k, off, 64);
            }
            if (k > 0.f){
                float tn = (s - 1.0f) / k;
                changed |= (tn != tau[r]);
                tau[r] = tn;
            }
        }
        if (!__any(changed)) break;
    }

    // PV: ctx[row quad*4+r][d = fr*4..fr*4+4] via ballot over sparse support
    float4 ctx[4];
    #pragma unroll
    for (int r=0;r<4;r++) ctx[r] = make_float4(0.f,0.f,0.f,0.f);
    const float* vb = V + hb;
    #pragma unroll
    for (int r=0;r<4;r++){
        #pragma unroll
        for (int j=0;j<32;j++){
            float p = acc[j][r] - tau[r];
            unsigned long long bal = __ballot(p > 0.f);
            unsigned mk = (unsigned)((bal >> (quad*16)) & 0xFFFFull);
            while (mk){
                int sf = __ffs(mk) - 1;
                mk &= mk - 1;
                float pv = __shfl(p, quad*16 + sf, 64);
                const float4 vv = *(const float4*)(vb + (size_t)(j*16 + sf)*DH_ + fr*4);
                ctx[r].x += pv * vv.x;
                ctx[r].y += pv * vv.y;
                ctx[r].z += pv * vv.z;
                ctx[r].w += pv * vv.w;
            }
        }
    }

    #pragma unroll
    for (int r=0;r<4;r++){
        int s = q0 + quad*4 + r;
        *(float4*)(out + ((size_t)(b*S_ + s))*D_ + h*DH_ + fr*4) = ctx[r];
    }
}

// ---------------------------------------------------------------------------
extern "C" void kernel_launch(void* const* d_in, const int* in_sizes, int n_in,
                              void* d_out, int out_size, void* d_ws, size_t ws_size,
                              hipStream_t stream) {
    const float* hs   = (const float*)d_in[0];
    const float* mask = (const float*)d_in[1];
    const float* Wq   = (const float*)d_in[2];
    const float* bq   = (const float*)d_in[3];
    const float* Wk   = (const float*)d_in[4];
    const float* bk   = (const float*)d_in[5];
    const float* Wv   = (const float*)d_in[6];
    const float* bv   = (const float*)d_in[7];
    float* out = (float*)d_out;

    const size_t per = (size_t)BH_ * S_ * DH_;   // 6291456
    char* w = (char*)d_ws;
    float*    vb  = (float*)w;    w += per*4;
    ushort_t* qhi = (ushort_t*)w; w += per*2;
    ushort_t* qlo = (ushort_t*)w; w += per*2;
    ushort_t* khi = (ushort_t*)w; w += per*2;
    ushort_t* klo = (ushort_t*)w; w += per*2;
    ushort_t* Xhi = (ushort_t*)w; w += per*2;
    ushort_t* Xlo = (ushort_t*)w; w += per*2;
    ushort_t* Whi = (ushort_t*)w; w += (size_t)NTOT*D_*2;
    ushort_t* Wlo = (ushort_t*)w;

    convert_hl<<<(int)(per/4/256), 256, 0, stream>>>(hs, Xhi, Xlo, (int)(per/4));
    convert_w<<<dim3(D_*D_/4/256, 1, 3), 256, 0, stream>>>(Wq, Wk, Wv, Whi, Wlo);

    dim3 ggrid(NTOT/BN, MTOT/BM);   // (18, 64)
    gemm_split<<<ggrid, 256, 0, stream>>>(Xhi, Xlo, Whi, Wlo, bq, bk, bv,
                                          qhi, qlo, khi, klo, vb);

    attn_mfma<<<BH_*8, 256, 0, stream>>>(qhi, qlo, khi, klo, vb, mask, out);
}

// Round 4
// 384.396 us; speedup vs baseline: 2.5852x; 1.0500x over previous
//
#include <hip/hip_runtime.h>
#include <math.h>

#define B_ 16
#define S_ 512
#define D_ 768
#define H_ 12
#define DH_ 64
#define BH_ (B_*H_)     // 192
#define MTOT (B_*S_)    // 8192
#define NTOT (3*D_)     // 2304

typedef unsigned short ushort_t;
typedef __attribute__((ext_vector_type(8))) short bf16x8;
typedef __attribute__((ext_vector_type(4))) float f32x4;

__device__ __forceinline__ unsigned short f2bf(float x){
    unsigned u = __float_as_uint(x);
    unsigned r = (u + 0x7FFFu + ((u >> 16) & 1u)) >> 16;
    return (unsigned short)r;
}
__device__ __forceinline__ float bf2f(unsigned short b){
    return __uint_as_float(((unsigned)b) << 16);
}

__device__ __forceinline__ void cp16(const void* g, void* l){
    __builtin_amdgcn_global_load_lds(
        (const __attribute__((address_space(1))) unsigned int*)g,
        (__attribute__((address_space(3))) unsigned int*)l, 16, 0, 0);
}

// ---------------------------------------------------------------------------
// f32 -> (hi, lo) bf16 split conversion, 4 elems/thread
// ---------------------------------------------------------------------------
__global__ __launch_bounds__(256)
void convert_hl(const float* __restrict__ src, ushort_t* __restrict__ hi,
                ushort_t* __restrict__ lo, int n4)
{
    int i = blockIdx.x * 256 + threadIdx.x;
    if (i >= n4) return;
    float4 x = ((const float4*)src)[i];
    union { ushort_t u[4]; uint2 v; } ph, pl;
    float xs[4] = {x.x, x.y, x.z, x.w};
    #pragma unroll
    for (int c = 0; c < 4; c++){
        unsigned short h = f2bf(xs[c]);
        ph.u[c] = h;
        pl.u[c] = f2bf(xs[c] - bf2f(h));
    }
    ((uint2*)hi)[i] = ph.v;
    ((uint2*)lo)[i] = pl.v;
}

__global__ __launch_bounds__(256)
void convert_w(const float* __restrict__ Wq, const float* __restrict__ Wk,
               const float* __restrict__ Wv, ushort_t* __restrict__ hi,
               ushort_t* __restrict__ lo)
{
    const float* src = (blockIdx.z==0) ? Wq : (blockIdx.z==1) ? Wk : Wv;
    const int n4 = D_*D_/4;
    int i = blockIdx.x * 256 + threadIdx.x;
    if (i >= n4) return;
    size_t off4 = (size_t)blockIdx.z * n4;
    float4 x = ((const float4*)src)[i];
    union { ushort_t u[4]; uint2 v; } ph, pl;
    float xs[4] = {x.x, x.y, x.z, x.w};
    #pragma unroll
    for (int c = 0; c < 4; c++){
        unsigned short h = f2bf(xs[c]);
        ph.u[c] = h;
        pl.u[c] = f2bf(xs[c] - bf2f(h));
    }
    ((uint2*)hi)[off4 + i] = ph.v;
    ((uint2*)lo)[off4 + i] = pl.v;
}

// ---------------------------------------------------------------------------
// Split-bf16 MFMA GEMM: C[m,n] = sum_k X[m,k] * W[n,k] + bias
// mat 0 -> Q hi/lo bf16, mat 1 -> K hi/lo bf16, mat 2 -> V f32; all [BH,S,DH]
// ---------------------------------------------------------------------------
#define BM 128
#define BN 128
#define BK 32

__global__ __launch_bounds__(256)
void gemm_split(const ushort_t* __restrict__ Ahi, const ushort_t* __restrict__ Alo,
                const ushort_t* __restrict__ Bhi, const ushort_t* __restrict__ Blo,
                const float* __restrict__ bq, const float* __restrict__ bk,
                const float* __restrict__ bv,
                ushort_t* __restrict__ qhi, ushort_t* __restrict__ qlo,
                ushort_t* __restrict__ khi, ushort_t* __restrict__ klo,
                float* __restrict__ outv)
{
    __shared__ ushort_t Ah[BM*BK], Al[BM*BK], Bh[BN*BK], Bl[BN*BK];

    const int tid  = threadIdx.x;
    const int lane = tid & 63, wave = tid >> 6;
    const int m0 = blockIdx.y * BM, n0 = blockIdx.x * BN;
    const int wm = (wave >> 1) * 64, wn = (wave & 1) * 64;

    f32x4 acc[4][4];
    #pragma unroll
    for (int i=0;i<4;i++)
        #pragma unroll
        for (int j=0;j<4;j++) acc[i][j] = (f32x4){0.f,0.f,0.f,0.f};

    const int r0 = tid >> 2, c0 = (tid & 3) * 8;
    const size_t ga0 = (size_t)(m0 + r0)      * D_ + c0;
    const size_t ga1 = (size_t)(m0 + 64 + r0) * D_ + c0;
    const size_t gb0 = (size_t)(n0 + r0)      * D_ + c0;
    const size_t gb1 = (size_t)(n0 + 64 + r0) * D_ + c0;
    const int l0 = wave * 512;
    const int l1 = 2048 + wave * 512;

    const int fr = lane & 15, kc = (lane >> 4) * 8;

    for (int k0 = 0; k0 < D_; k0 += BK) {
        cp16(Ahi + ga0 + k0, Ah + l0);
        cp16(Ahi + ga1 + k0, Ah + l1);
        cp16(Alo + ga0 + k0, Al + l0);
        cp16(Alo + ga1 + k0, Al + l1);
        cp16(Bhi + gb0 + k0, Bh + l0);
        cp16(Bhi + gb1 + k0, Bh + l1);
        cp16(Blo + gb0 + k0, Bl + l0);
        cp16(Blo + gb1 + k0, Bl + l1);
        __syncthreads();

        bf16x8 fah[4], fal[4], fbh[4], fbl[4];
        #pragma unroll
        for (int i = 0; i < 4; i++){
            fah[i] = *(const bf16x8*)&Ah[(wm + i*16 + fr)*BK + kc];
            fal[i] = *(const bf16x8*)&Al[(wm + i*16 + fr)*BK + kc];
            fbh[i] = *(const bf16x8*)&Bh[(wn + i*16 + fr)*BK + kc];
            fbl[i] = *(const bf16x8*)&Bl[(wn + i*16 + fr)*BK + kc];
        }
        #pragma unroll
        for (int i = 0; i < 4; i++)
            #pragma unroll
            for (int j = 0; j < 4; j++){
                acc[i][j] = __builtin_amdgcn_mfma_f32_16x16x32_bf16(fah[i], fbh[j], acc[i][j], 0,0,0);
                acc[i][j] = __builtin_amdgcn_mfma_f32_16x16x32_bf16(fah[i], fbl[j], acc[i][j], 0,0,0);
                acc[i][j] = __builtin_amdgcn_mfma_f32_16x16x32_bf16(fal[i], fbh[j], acc[i][j], 0,0,0);
            }
        __syncthreads();
    }

    const int mat = n0 / D_;   // block-uniform
    const float* bias = (mat==0) ? bq : (mat==1) ? bk : bv;
    const int col = lane & 15, rbase = (lane >> 4) * 4;
    #pragma unroll
    for (int j = 0; j < 4; j++){
        int nn = n0 + wn + j*16 + col - mat*D_;
        int h = nn >> 6, d = nn & 63;
        float bsv = bias[nn];
        #pragma unroll
        for (int i = 0; i < 4; i++){
            #pragma unroll
            for (int r = 0; r < 4; r++){
                int m = m0 + wm + i*16 + rbase + r;
                int bb = m >> 9, s = m & 511;
                size_t idx = (((size_t)bb*H_ + h)*S_ + s)*DH_ + d;
                float val = acc[i][j][r] + bsv;
                if (mat == 2) outv[idx] = val;
                else {
                    ushort_t hv = f2bf(val);
                    ushort_t lv = f2bf(val - bf2f(hv));
                    if (mat == 0){ qhi[idx] = hv; qlo[idx] = lv; }
                    else         { khi[idx] = hv; klo[idx] = lv; }
                }
            }
        }
    }
}

// ---------------------------------------------------------------------------
// MFMA sparsemax attention, key-split across waves.
// Block = (head, 16 q-rows); wave w owns keys [128w, 128w+128) -> acc[8].
// C layout: col(lane&15)=key%16, row=quad*4+reg. Cross-wave tau via LDS.
// ---------------------------------------------------------------------------
#define NIT 16

__global__ __launch_bounds__(256)
void attn_mfma(const ushort_t* __restrict__ Qhi, const ushort_t* __restrict__ Qlo,
               const ushort_t* __restrict__ Khi, const ushort_t* __restrict__ Klo,
               const float* __restrict__ V, const float* __restrict__ mask,
               float* __restrict__ out)
{
    __shared__ float2 red[2][4][16];     // [parity][wave][row] (sum,count)|max
    __shared__ float  cpart[4][16][64];  // PV partials, 16 KB
    __shared__ int    flags[NIT];

    const int lane = threadIdx.x & 63;
    const int wave = threadIdx.x >> 6;
    const int fr = lane & 15, quad = lane >> 4;
    const int bh = blockIdx.x >> 5;            // 32 blocks per head
    const int q0 = (blockIdx.x & 31) * 16;
    const int b = bh / H_, h = bh % H_;
    const size_t hb = (size_t)bh * S_ * DH_;
    const int kw0 = wave * 128;                // this wave's key range

    if (threadIdx.x < NIT) flags[threadIdx.x] = 0;

    // Q A-fragments: row = fr (q0+fr), k = quad*8 + [0..8)
    bf16x8 qh[2], ql[2];
    {
        const ushort_t* qp  = Qhi + hb + (size_t)(q0 + fr)*DH_ + quad*8;
        const ushort_t* qp2 = Qlo + hb + (size_t)(q0 + fr)*DH_ + quad*8;
        qh[0] = *(const bf16x8*)qp;   qh[1] = *(const bf16x8*)(qp + 32);
        ql[0] = *(const bf16x8*)qp2;  ql[1] = *(const bf16x8*)(qp2 + 32);
    }

    // scores for this wave's 8 key-tiles
    f32x4 acc[8];
    #pragma unroll
    for (int j=0;j<8;j++) acc[j] = (f32x4){0.f,0.f,0.f,0.f};

    #pragma unroll
    for (int j=0;j<8;j++){
        const ushort_t* kp  = Khi + hb + (size_t)(kw0 + j*16 + fr)*DH_ + quad*8;
        const ushort_t* kp2 = Klo + hb + (size_t)(kw0 + j*16 + fr)*DH_ + quad*8;
        bf16x8 kh0 = *(const bf16x8*)kp;
        bf16x8 kh1 = *(const bf16x8*)(kp + 32);
        bf16x8 kl0 = *(const bf16x8*)kp2;
        bf16x8 kl1 = *(const bf16x8*)(kp2 + 32);
        acc[j] = __builtin_amdgcn_mfma_f32_16x16x32_bf16(qh[0], kh0, acc[j], 0,0,0);
        acc[j] = __builtin_amdgcn_mfma_f32_16x16x32_bf16(qh[1], kh1, acc[j], 0,0,0);
        acc[j] = __builtin_amdgcn_mfma_f32_16x16x32_bf16(ql[0], kh0, acc[j], 0,0,0);
        acc[j] = __builtin_amdgcn_mfma_f32_16x16x32_bf16(ql[1], kh1, acc[j], 0,0,0);
        acc[j] = __builtin_amdgcn_mfma_f32_16x16x32_bf16(qh[0], kl0, acc[j], 0,0,0);
        acc[j] = __builtin_amdgcn_mfma_f32_16x16x32_bf16(qh[1], kl1, acc[j], 0,0,0);
    }

    // scale + mask (key = kw0 + j*16 + fr)
    const float* mrow = mask + b * S_;
    #pragma unroll
    for (int j=0;j<8;j++){
        float mv = mrow[kw0 + j*16 + fr];
        #pragma unroll
        for (int r=0;r<4;r++) acc[j][r] = acc[j][r]*0.125f + mv;
    }

    // per-row max: local over 8 tiles + 16-lane shfl, then cross-wave via LDS
    float tau[4];
    #pragma unroll
    for (int r=0;r<4;r++){
        float m = acc[0][r];
        #pragma unroll
        for (int j=1;j<8;j++) m = fmaxf(m, acc[j][r]);
        #pragma unroll
        for (int off=1; off<16; off<<=1) m = fmaxf(m, __shfl_xor(m, off, 64));
        if (fr == 0) red[0][wave][quad*4+r] = make_float2(m, 0.f);
        tau[r] = m;
    }
    __syncthreads();
    #pragma unroll
    for (int r=0;r<4;r++){
        int row = quad*4 + r;
        float m = red[0][0][row].x;
        #pragma unroll
        for (int ww=1; ww<4; ww++) m = fmaxf(m, red[0][ww][row].x);
        tau[r] = m - 1.0f;
    }

    // Michelot fixed-point: tau <- (sum_{z>tau} z - 1)/count. 2 barriers/iter,
    // early-exit via monotone flags[] (double-buffered red[] parity).
    for (int it=0; it<NIT; it++){
        int p = (it + 1) & 1;
        #pragma unroll
        for (int r=0;r<4;r++){
            float s = 0.f, k = 0.f;
            #pragma unroll
            for (int j=0;j<8;j++){
                float z = acc[j][r];
                if (z > tau[r]){ s += z; k += 1.f; }
            }
            #pragma unroll
            for (int off=1; off<16; off<<=1){
                s += __shfl_xor(s, off, 64);
                k += __shfl_xor(k, off, 64);
            }
            if (fr == 0) red[p][wave][quad*4+r] = make_float2(s, k);
        }
        __syncthreads();
        bool changed = false;
        #pragma unroll
        for (int r=0;r<4;r++){
            int row = quad*4 + r;
            float S = 0.f, K = 0.f;
            #pragma unroll
            for (int ww=0; ww<4; ww++){
                float2 f2 = red[p][ww][row];
                S += f2.x; K += f2.y;
            }
            if (K > 0.f){
                float tn = (S - 1.0f) / K;
                changed |= (tn != tau[r]);
                tau[r] = tn;
            }
        }
        if (__any(changed) && lane == 0) flags[it] = 1;
        __syncthreads();
        if (!flags[it]) break;
    }

    // PV partials over this wave's 128 keys (ballot-sparse, coalesced V rows)
    float4 ctx[4];
    #pragma unroll
    for (int r=0;r<4;r++) ctx[r] = make_float4(0.f,0.f,0.f,0.f);
    const float* vb = V + hb;
    #pragma unroll
    for (int r=0;r<4;r++){
        #pragma unroll
        for (int j=0;j<8;j++){
            float pcur = acc[j][r] - tau[r];
            unsigned long long bal = __ballot(pcur > 0.f);
            unsigned mk = (unsigned)((bal >> (quad*16)) & 0xFFFFull);
            while (mk){
                int sf = __ffs(mk) - 1;
                mk &= mk - 1;
                float pv = __shfl(pcur, quad*16 + sf, 64);
                const float4 vv = *(const float4*)(vb + (size_t)(kw0 + j*16 + sf)*DH_ + fr*4);
                ctx[r].x += pv * vv.x;
                ctx[r].y += pv * vv.y;
                ctx[r].z += pv * vv.z;
                ctx[r].w += pv * vv.w;
            }
        }
    }
    #pragma unroll
    for (int r=0;r<4;r++)
        *(float4*)&cpart[wave][quad*4 + r][fr*4] = ctx[r];
    __syncthreads();

    // final cross-wave sum + store: thread -> (row, 4 d-cols)
    {
        int row = threadIdx.x >> 4;
        int d4  = (threadIdx.x & 15) * 4;
        float4 s0 = *(const float4*)&cpart[0][row][d4];
        float4 s1 = *(const float4*)&cpart[1][row][d4];
        float4 s2 = *(const float4*)&cpart[2][row][d4];
        float4 s3 = *(const float4*)&cpart[3][row][d4];
        float4 o;
        o.x = s0.x + s1.x + s2.x + s3.x;
        o.y = s0.y + s1.y + s2.y + s3.y;
        o.z = s0.z + s1.z + s2.z + s3.z;
        o.w = s0.w + s1.w + s2.w + s3.w;
        *(float4*)(out + ((size_t)(b*S_ + q0 + row))*D_ + h*DH_ + d4) = o;
    }
}

// ---------------------------------------------------------------------------
extern "C" void kernel_launch(void* const* d_in, const int* in_sizes, int n_in,
                              void* d_out, int out_size, void* d_ws, size_t ws_size,
                              hipStream_t stream) {
    const float* hs   = (const float*)d_in[0];
    const float* mask = (const float*)d_in[1];
    const float* Wq   = (const float*)d_in[2];
    const float* bq   = (const float*)d_in[3];
    const float* Wk   = (const float*)d_in[4];
    const float* bk   = (const float*)d_in[5];
    const float* Wv   = (const float*)d_in[6];
    const float* bv   = (const float*)d_in[7];
    float* out = (float*)d_out;

    const size_t per = (size_t)BH_ * S_ * DH_;   // 6291456
    char* w = (char*)d_ws;
    float*    vb  = (float*)w;    w += per*4;
    ushort_t* qhi = (ushort_t*)w; w += per*2;
    ushort_t* qlo = (ushort_t*)w; w += per*2;
    ushort_t* khi = (ushort_t*)w; w += per*2;
    ushort_t* klo = (ushort_t*)w; w += per*2;
    ushort_t* Xhi = (ushort_t*)w; w += per*2;
    ushort_t* Xlo = (ushort_t*)w; w += per*2;
    ushort_t* Whi = (ushort_t*)w; w += (size_t)NTOT*D_*2;
    ushort_t* Wlo = (ushort_t*)w;

    convert_hl<<<(int)(per/4/256), 256, 0, stream>>>(hs, Xhi, Xlo, (int)(per/4));
    convert_w<<<dim3(D_*D_/4/256, 1, 3), 256, 0, stream>>>(Wq, Wk, Wv, Whi, Wlo);

    dim3 ggrid(NTOT/BN, MTOT/BM);   // (18, 64)
    gemm_split<<<ggrid, 256, 0, stream>>>(Xhi, Xlo, Whi, Wlo, bq, bk, bv,
                                          qhi, qlo, khi, klo, vb);

    attn_mfma<<<BH_*32, 256, 0, stream>>>(qhi, qlo, khi, klo, vb, mask, out);
}

// Round 5
// 362.440 us; speedup vs baseline: 2.7419x; 1.0606x over previous
//
#include <hip/hip_runtime.h>
#include <math.h>

#define B_ 16
#define S_ 512
#define D_ 768
#define H_ 12
#define DH_ 64
#define BH_ (B_*H_)     // 192
#define MTOT (B_*S_)    // 8192
#define NTOT (3*D_)     // 2304

typedef unsigned short ushort_t;
typedef __attribute__((ext_vector_type(8))) short bf16x8;
typedef __attribute__((ext_vector_type(4))) float f32x4;

__device__ __forceinline__ unsigned short f2bf(float x){
    unsigned u = __float_as_uint(x);
    unsigned r = (u + 0x7FFFu + ((u >> 16) & 1u)) >> 16;
    return (unsigned short)r;
}
__device__ __forceinline__ float bf2f(unsigned short b){
    return __uint_as_float(((unsigned)b) << 16);
}

__device__ __forceinline__ void cp16(const void* g, void* l){
    __builtin_amdgcn_global_load_lds(
        (const __attribute__((address_space(1))) unsigned int*)g,
        (__attribute__((address_space(3))) unsigned int*)l, 16, 0, 0);
}

// ---------------------------------------------------------------------------
// f32 -> (hi, lo) bf16 split conversion, 4 elems/thread
// ---------------------------------------------------------------------------
__global__ __launch_bounds__(256)
void convert_hl(const float* __restrict__ src, ushort_t* __restrict__ hi,
                ushort_t* __restrict__ lo, int n4)
{
    int i = blockIdx.x * 256 + threadIdx.x;
    if (i >= n4) return;
    float4 x = ((const float4*)src)[i];
    union { ushort_t u[4]; uint2 v; } ph, pl;
    float xs[4] = {x.x, x.y, x.z, x.w};
    #pragma unroll
    for (int c = 0; c < 4; c++){
        unsigned short h = f2bf(xs[c]);
        ph.u[c] = h;
        pl.u[c] = f2bf(xs[c] - bf2f(h));
    }
    ((uint2*)hi)[i] = ph.v;
    ((uint2*)lo)[i] = pl.v;
}

__global__ __launch_bounds__(256)
void convert_w(const float* __restrict__ Wq, const float* __restrict__ Wk,
               const float* __restrict__ Wv, ushort_t* __restrict__ hi,
               ushort_t* __restrict__ lo)
{
    const float* src = (blockIdx.z==0) ? Wq : (blockIdx.z==1) ? Wk : Wv;
    const int n4 = D_*D_/4;
    int i = blockIdx.x * 256 + threadIdx.x;
    if (i >= n4) return;
    size_t off4 = (size_t)blockIdx.z * n4;
    float4 x = ((const float4*)src)[i];
    union { ushort_t u[4]; uint2 v; } ph, pl;
    float xs[4] = {x.x, x.y, x.z, x.w};
    #pragma unroll
    for (int c = 0; c < 4; c++){
        unsigned short h = f2bf(xs[c]);
        ph.u[c] = h;
        pl.u[c] = f2bf(xs[c] - bf2f(h));
    }
    ((uint2*)hi)[off4 + i] = ph.v;
    ((uint2*)lo)[off4 + i] = pl.v;
}

// ---------------------------------------------------------------------------
// Split-bf16 MFMA GEMM: C[m,n] = sum_k X[m,k] * W[n,k] + bias
// mat 0 -> Q hi/lo bf16, mat 1 -> K hi/lo bf16, mat 2 -> V f32; all [BH,S,DH]
// ---------------------------------------------------------------------------
#define BM 128
#define BN 128
#define BK 32

__global__ __launch_bounds__(256)
void gemm_split(const ushort_t* __restrict__ Ahi, const ushort_t* __restrict__ Alo,
                const ushort_t* __restrict__ Bhi, const ushort_t* __restrict__ Blo,
                const float* __restrict__ bq, const float* __restrict__ bk,
                const float* __restrict__ bv,
                ushort_t* __restrict__ qhi, ushort_t* __restrict__ qlo,
                ushort_t* __restrict__ khi, ushort_t* __restrict__ klo,
                float* __restrict__ outv)
{
    __shared__ ushort_t Ah[BM*BK], Al[BM*BK], Bh[BN*BK], Bl[BN*BK];

    const int tid  = threadIdx.x;
    const int lane = tid & 63, wave = tid >> 6;
    const int m0 = blockIdx.y * BM, n0 = blockIdx.x * BN;
    const int wm = (wave >> 1) * 64, wn = (wave & 1) * 64;

    f32x4 acc[4][4];
    #pragma unroll
    for (int i=0;i<4;i++)
        #pragma unroll
        for (int j=0;j<4;j++) acc[i][j] = (f32x4){0.f,0.f,0.f,0.f};

    const int r0 = tid >> 2, c0 = (tid & 3) * 8;
    const size_t ga0 = (size_t)(m0 + r0)      * D_ + c0;
    const size_t ga1 = (size_t)(m0 + 64 + r0) * D_ + c0;
    const size_t gb0 = (size_t)(n0 + r0)      * D_ + c0;
    const size_t gb1 = (size_t)(n0 + 64 + r0) * D_ + c0;
    const int l0 = wave * 512;
    const int l1 = 2048 + wave * 512;

    const int fr = lane & 15, kc = (lane >> 4) * 8;

    for (int k0 = 0; k0 < D_; k0 += BK) {
        cp16(Ahi + ga0 + k0, Ah + l0);
        cp16(Ahi + ga1 + k0, Ah + l1);
        cp16(Alo + ga0 + k0, Al + l0);
        cp16(Alo + ga1 + k0, Al + l1);
        cp16(Bhi + gb0 + k0, Bh + l0);
        cp16(Bhi + gb1 + k0, Bh + l1);
        cp16(Blo + gb0 + k0, Bl + l0);
        cp16(Blo + gb1 + k0, Bl + l1);
        __syncthreads();

        bf16x8 fah[4], fal[4], fbh[4], fbl[4];
        #pragma unroll
        for (int i = 0; i < 4; i++){
            fah[i] = *(const bf16x8*)&Ah[(wm + i*16 + fr)*BK + kc];
            fal[i] = *(const bf16x8*)&Al[(wm + i*16 + fr)*BK + kc];
            fbh[i] = *(const bf16x8*)&Bh[(wn + i*16 + fr)*BK + kc];
            fbl[i] = *(const bf16x8*)&Bl[(wn + i*16 + fr)*BK + kc];
        }
        #pragma unroll
        for (int i = 0; i < 4; i++)
            #pragma unroll
            for (int j = 0; j < 4; j++){
                acc[i][j] = __builtin_amdgcn_mfma_f32_16x16x32_bf16(fah[i], fbh[j], acc[i][j], 0,0,0);
                acc[i][j] = __builtin_amdgcn_mfma_f32_16x16x32_bf16(fah[i], fbl[j], acc[i][j], 0,0,0);
                acc[i][j] = __builtin_amdgcn_mfma_f32_16x16x32_bf16(fal[i], fbh[j], acc[i][j], 0,0,0);
            }
        __syncthreads();
    }

    const int mat = n0 / D_;   // block-uniform
    const float* bias = (mat==0) ? bq : (mat==1) ? bk : bv;
    const int col = lane & 15, rbase = (lane >> 4) * 4;
    #pragma unroll
    for (int j = 0; j < 4; j++){
        int nn = n0 + wn + j*16 + col - mat*D_;
        int h = nn >> 6, d = nn & 63;
        float bsv = bias[nn];
        #pragma unroll
        for (int i = 0; i < 4; i++){
            #pragma unroll
            for (int r = 0; r < 4; r++){
                int m = m0 + wm + i*16 + rbase + r;
                int bb = m >> 9, s = m & 511;
                size_t idx = (((size_t)bb*H_ + h)*S_ + s)*DH_ + d;
                float val = acc[i][j][r] + bsv;
                if (mat == 2) outv[idx] = val;
                else {
                    ushort_t hv = f2bf(val);
                    ushort_t lv = f2bf(val - bf2f(hv));
                    if (mat == 0){ qhi[idx] = hv; qlo[idx] = lv; }
                    else         { khi[idx] = hv; klo[idx] = lv; }
                }
            }
        }
    }
}

// ---------------------------------------------------------------------------
// MFMA sparsemax attention, v3: one barrier, then wave-owned complete rows.
// Phase 1: wave w computes scores for 16 rows x keys [128w,128w+128) -> LDS.
// Phase 2: wave w owns rows 4w..4w+3 (full 512 keys), does Michelot tau +
//          ballot-sparse PV entirely wave-locally, writes out directly.
// ---------------------------------------------------------------------------
#define SCPAD 524   // stride: 4*524 % 32 == 16 -> 2-way on write (free)

__global__ __launch_bounds__(256)
void attn_mfma(const ushort_t* __restrict__ Qhi, const ushort_t* __restrict__ Qlo,
               const ushort_t* __restrict__ Khi, const ushort_t* __restrict__ Klo,
               const float* __restrict__ V, const float* __restrict__ mask,
               float* __restrict__ out)
{
    __shared__ float sc[16*SCPAD];   // 33.5 KB scores [row][key]

    const int lane = threadIdx.x & 63;
    const int wave = threadIdx.x >> 6;
    const int fr = lane & 15, quad = lane >> 4;
    const int bh = blockIdx.x >> 5;            // 32 blocks per head
    const int q0 = (blockIdx.x & 31) * 16;
    const int b = bh / H_, h = bh % H_;
    const size_t hb = (size_t)bh * S_ * DH_;
    const int kw0 = wave * 128;                // phase-1 key range

    // Q A-fragments: row = fr (q0+fr), k = quad*8 + [0..8)
    bf16x8 qh[2], ql[2];
    {
        const ushort_t* qp  = Qhi + hb + (size_t)(q0 + fr)*DH_ + quad*8;
        const ushort_t* qp2 = Qlo + hb + (size_t)(q0 + fr)*DH_ + quad*8;
        qh[0] = *(const bf16x8*)qp;   qh[1] = *(const bf16x8*)(qp + 32);
        ql[0] = *(const bf16x8*)qp2;  ql[1] = *(const bf16x8*)(qp2 + 32);
    }

    f32x4 acc[8];
    #pragma unroll
    for (int j=0;j<8;j++) acc[j] = (f32x4){0.f,0.f,0.f,0.f};

    #pragma unroll
    for (int j=0;j<8;j++){
        const ushort_t* kp  = Khi + hb + (size_t)(kw0 + j*16 + fr)*DH_ + quad*8;
        const ushort_t* kp2 = Klo + hb + (size_t)(kw0 + j*16 + fr)*DH_ + quad*8;
        bf16x8 kh0 = *(const bf16x8*)kp;
        bf16x8 kh1 = *(const bf16x8*)(kp + 32);
        bf16x8 kl0 = *(const bf16x8*)kp2;
        bf16x8 kl1 = *(const bf16x8*)(kp2 + 32);
        acc[j] = __builtin_amdgcn_mfma_f32_16x16x32_bf16(qh[0], kh0, acc[j], 0,0,0);
        acc[j] = __builtin_amdgcn_mfma_f32_16x16x32_bf16(qh[1], kh1, acc[j], 0,0,0);
        acc[j] = __builtin_amdgcn_mfma_f32_16x16x32_bf16(ql[0], kh0, acc[j], 0,0,0);
        acc[j] = __builtin_amdgcn_mfma_f32_16x16x32_bf16(ql[1], kh1, acc[j], 0,0,0);
        acc[j] = __builtin_amdgcn_mfma_f32_16x16x32_bf16(qh[0], kl0, acc[j], 0,0,0);
        acc[j] = __builtin_amdgcn_mfma_f32_16x16x32_bf16(qh[1], kl1, acc[j], 0,0,0);
    }

    // scale + mask, scatter to LDS (C layout: row=quad*4+r, key=kw0+j*16+fr)
    const float* mrow = mask + b * S_;
    #pragma unroll
    for (int j=0;j<8;j++){
        float mv = mrow[kw0 + j*16 + fr];
        #pragma unroll
        for (int r=0;r<4;r++)
            sc[(quad*4 + r)*SCPAD + kw0 + j*16 + fr] = acc[j][r]*0.125f + mv;
    }
    __syncthreads();

    // wave w owns rows 4w..4w+3; lane l holds keys [8l, 8l+8) of each row
    float z[4][8];
    #pragma unroll
    for (int r=0;r<4;r++){
        const float* p = &sc[(wave*4 + r)*SCPAD + lane*8];
        float4 a = *(const float4*)p;
        float4 c = *(const float4*)(p + 4);
        z[r][0]=a.x; z[r][1]=a.y; z[r][2]=a.z; z[r][3]=a.w;
        z[r][4]=c.x; z[r][5]=c.y; z[r][6]=c.z; z[r][7]=c.w;
    }

    // per-row max (lockstep, 4 independent shfl chains)
    float tau[4];
    {
        float m[4];
        #pragma unroll
        for (int r=0;r<4;r++){
            float mm = z[r][0];
            #pragma unroll
            for (int i=1;i<8;i++) mm = fmaxf(mm, z[r][i]);
            m[r] = mm;
        }
        #pragma unroll
        for (int off=1; off<64; off<<=1){
            #pragma unroll
            for (int r=0;r<4;r++) m[r] = fmaxf(m[r], __shfl_xor(m[r], off, 64));
        }
        #pragma unroll
        for (int r=0;r<4;r++) tau[r] = m[r] - 1.0f;
    }

    // Michelot fixed-point, wave-local lockstep over 4 rows; exits on exact
    // wave-uniform fixpoint. No barriers.
    for (int it=0; it<16; it++){
        float s[4], k[4];
        #pragma unroll
        for (int r=0;r<4;r++){
            float ss = 0.f, kk = 0.f;
            #pragma unroll
            for (int i=0;i<8;i++){
                float zz = z[r][i];
                if (zz > tau[r]){ ss += zz; kk += 1.f; }
            }
            s[r] = ss; k[r] = kk;
        }
        #pragma unroll
        for (int off=1; off<64; off<<=1){
            #pragma unroll
            for (int r=0;r<4;r++){
                s[r] += __shfl_xor(s[r], off, 64);
                k[r] += __shfl_xor(k[r], off, 64);
            }
        }
        bool any = false;
        #pragma unroll
        for (int r=0;r<4;r++){
            float tn = (s[r] - 1.0f) / k[r];   // k>=1: max always in support
            any |= (tn != tau[r]);
            tau[r] = tn;
        }
        if (!any) break;                       // wave-uniform
    }

    // PV: ballot-sparse gather; key = 8*src + i; V row read coalesced (256B)
    float ctx[4] = {0.f, 0.f, 0.f, 0.f};
    const float* vb = V + hb;
    #pragma unroll
    for (int r=0;r<4;r++){
        #pragma unroll
        for (int i=0;i<8;i++){
            float p = fmaxf(z[r][i] - tau[r], 0.f);
            unsigned long long mk = __ballot(p > 0.f);
            while (mk){
                int src = __ffsll((long long)mk) - 1;
                mk &= mk - 1;
                float pv = __shfl(p, src, 64);
                ctx[r] += pv * vb[(size_t)(src*8 + i)*DH_ + lane];
            }
        }
    }

    #pragma unroll
    for (int r=0;r<4;r++)
        out[((size_t)(b*S_ + q0 + wave*4 + r))*D_ + h*DH_ + lane] = ctx[r];
}

// ---------------------------------------------------------------------------
extern "C" void kernel_launch(void* const* d_in, const int* in_sizes, int n_in,
                              void* d_out, int out_size, void* d_ws, size_t ws_size,
                              hipStream_t stream) {
    const float* hs   = (const float*)d_in[0];
    const float* mask = (const float*)d_in[1];
    const float* Wq   = (const float*)d_in[2];
    const float* bq   = (const float*)d_in[3];
    const float* Wk   = (const float*)d_in[4];
    const float* bk   = (const float*)d_in[5];
    const float* Wv   = (const float*)d_in[6];
    const float* bv   = (const float*)d_in[7];
    float* out = (float*)d_out;

    const size_t per = (size_t)BH_ * S_ * DH_;   // 6291456
    char* w = (char*)d_ws;
    float*    vb  = (float*)w;    w += per*4;
    ushort_t* qhi = (ushort_t*)w; w += per*2;
    ushort_t* qlo = (ushort_t*)w; w += per*2;
    ushort_t* khi = (ushort_t*)w; w += per*2;
    ushort_t* klo = (ushort_t*)w; w += per*2;
    ushort_t* Xhi = (ushort_t*)w; w += per*2;
    ushort_t* Xlo = (ushort_t*)w; w += per*2;
    ushort_t* Whi = (ushort_t*)w; w += (size_t)NTOT*D_*2;
    ushort_t* Wlo = (ushort_t*)w;

    convert_hl<<<(int)(per/4/256), 256, 0, stream>>>(hs, Xhi, Xlo, (int)(per/4));
    convert_w<<<dim3(D_*D_/4/256, 1, 3), 256, 0, stream>>>(Wq, Wk, Wv, Whi, Wlo);

    dim3 ggrid(NTOT/BN, MTOT/BM);   // (18, 64)
    gemm_split<<<ggrid, 256, 0, stream>>>(Xhi, Xlo, Whi, Wlo, bq, bk, bv,
                                          qhi, qlo, khi, klo, vb);

    attn_mfma<<<BH_*32, 256, 0, stream>>>(qhi, qlo, khi, klo, vb, mask, out);
}